// Round 2
// baseline (1817.404 us; speedup 1.0000x reference)
//
#include <hip/hip_runtime.h>
#include <cstdint>

#define EPS 1e-6f

constexpr int Bsz = 4, Hn = 16, Lseq = 8192, Dd = 64;
constexpr int BH = Bsz * Hn;              // 64
constexpr int CHUNK = 128;                // rows per wave-chunk
constexpr int CPB = Lseq / CHUNK;         // 64 chunks per (b,h)
constexpr int NCHUNKS = BH * CPB;         // 4096
constexpr int WPB = 4;                    // waves per block
constexpr int NBLK = NCHUNKS / WPB;       // 1024 blocks

// feature map: x>0 ? x+1 : exp(x). __expf -> v_exp_f32
__device__ __forceinline__ float phi(float x) {
    return x > 0.0f ? x + 1.0f : __expf(x);
}

// Single-pass linear-attention scan with decoupled lookback.
// One wave = one 128-row chunk of one (b,h). flag: 0=empty, 1=aggregate
// ready (aggK/aggKV), 2=inclusive prefix ready (prefK/prefKV).
__global__ __launch_bounds__(256, 4) void la_onepass(
    const float* __restrict__ q, const float* __restrict__ k,
    const float* __restrict__ v, const float* __restrict__ mask,
    int* __restrict__ flags, int* __restrict__ ticket,
    float* __restrict__ aggK, float* __restrict__ aggKV,
    float* __restrict__ prefK, float* __restrict__ prefKV,
    float* __restrict__ out)
{
    // ticket: virtual block id in execution-start order => lookback on
    // smaller ids can never deadlock (their blocks already started).
    __shared__ int s_vb;
    if (threadIdx.x == 0) s_vb = atomicAdd(ticket, 1);
    __syncthreads();
    const int wave = s_vb * WPB + (int)(threadIdx.x >> 6);
    const int lane = threadIdx.x & 63;
    const int rg = lane >> 4;          // row group 0..3
    const int dg = lane & 15;          // dims [4*dg, 4*dg+4)
    const int bh = wave / CPB;
    const int c  = wave % CPB;
    const int b  = bh / Hn;
    const int l0 = c * CHUNK;

    // ---------------- phase 1: local chunk aggregate ----------------
    // backward over rows so the head of the chunk is cache-warm for phase 3
    float4 ak  = make_float4(0.f, 0.f, 0.f, 0.f);
    float4 akv = make_float4(0.f, 0.f, 0.f, 0.f);
    #pragma unroll 4
    for (int i = CHUNK - 4; i >= 0; i -= 4) {
        const int l = l0 + i + rg;
        const size_t off = ((size_t)bh * Lseq + l) * Dd + dg * 4;
        const float4 k4 = *(const float4*)(k + off);
        const float4 v4 = *(const float4*)(v + off);
        const float m = mask[(size_t)b * Lseq + l];
        float t;
        t = phi(k4.x) * m; ak.x += t; akv.x += t * (v4.x * m);
        t = phi(k4.y) * m; ak.y += t; akv.y += t * (v4.y * m);
        t = phi(k4.z) * m; ak.z += t; akv.z += t * (v4.z * m);
        t = phi(k4.w) * m; ak.w += t; akv.w += t * (v4.w * m);
    }
    #pragma unroll
    for (int o = 16; o <= 32; o <<= 1) {
        ak.x  += __shfl_xor(ak.x,  o, 64);
        ak.y  += __shfl_xor(ak.y,  o, 64);
        ak.z  += __shfl_xor(ak.z,  o, 64);
        ak.w  += __shfl_xor(ak.w,  o, 64);
        akv.x += __shfl_xor(akv.x, o, 64);
        akv.y += __shfl_xor(akv.y, o, 64);
        akv.z += __shfl_xor(akv.z, o, 64);
        akv.w += __shfl_xor(akv.w, o, 64);
    }

    // ---------------- publish + lookback ----------------
    const size_t pbase = (size_t)wave * Dd + dg * 4;
    float4 P   = make_float4(0.f, 0.f, 0.f, 0.f);   // exclusive prefix
    float4 Pkv = make_float4(0.f, 0.f, 0.f, 0.f);

    if (c == 0) {
        if (rg == 0) {
            __hip_atomic_store(prefK  + pbase + 0, ak.x,  __ATOMIC_RELAXED, __HIP_MEMORY_SCOPE_AGENT);
            __hip_atomic_store(prefK  + pbase + 1, ak.y,  __ATOMIC_RELAXED, __HIP_MEMORY_SCOPE_AGENT);
            __hip_atomic_store(prefK  + pbase + 2, ak.z,  __ATOMIC_RELAXED, __HIP_MEMORY_SCOPE_AGENT);
            __hip_atomic_store(prefK  + pbase + 3, ak.w,  __ATOMIC_RELAXED, __HIP_MEMORY_SCOPE_AGENT);
            __hip_atomic_store(prefKV + pbase + 0, akv.x, __ATOMIC_RELAXED, __HIP_MEMORY_SCOPE_AGENT);
            __hip_atomic_store(prefKV + pbase + 1, akv.y, __ATOMIC_RELAXED, __HIP_MEMORY_SCOPE_AGENT);
            __hip_atomic_store(prefKV + pbase + 2, akv.z, __ATOMIC_RELAXED, __HIP_MEMORY_SCOPE_AGENT);
            __hip_atomic_store(prefKV + pbase + 3, akv.w, __ATOMIC_RELAXED, __HIP_MEMORY_SCOPE_AGENT);
        }
        __threadfence();
        if (lane == 0)
            __hip_atomic_store(flags + wave, 2, __ATOMIC_RELAXED, __HIP_MEMORY_SCOPE_AGENT);
    } else {
        if (rg == 0) {
            __hip_atomic_store(aggK  + pbase + 0, ak.x,  __ATOMIC_RELAXED, __HIP_MEMORY_SCOPE_AGENT);
            __hip_atomic_store(aggK  + pbase + 1, ak.y,  __ATOMIC_RELAXED, __HIP_MEMORY_SCOPE_AGENT);
            __hip_atomic_store(aggK  + pbase + 2, ak.z,  __ATOMIC_RELAXED, __HIP_MEMORY_SCOPE_AGENT);
            __hip_atomic_store(aggK  + pbase + 3, ak.w,  __ATOMIC_RELAXED, __HIP_MEMORY_SCOPE_AGENT);
            __hip_atomic_store(aggKV + pbase + 0, akv.x, __ATOMIC_RELAXED, __HIP_MEMORY_SCOPE_AGENT);
            __hip_atomic_store(aggKV + pbase + 1, akv.y, __ATOMIC_RELAXED, __HIP_MEMORY_SCOPE_AGENT);
            __hip_atomic_store(aggKV + pbase + 2, akv.z, __ATOMIC_RELAXED, __HIP_MEMORY_SCOPE_AGENT);
            __hip_atomic_store(aggKV + pbase + 3, akv.w, __ATOMIC_RELAXED, __HIP_MEMORY_SCOPE_AGENT);
        }
        __threadfence();
        if (lane == 0)
            __hip_atomic_store(flags + wave, 1, __ATOMIC_RELAXED, __HIP_MEMORY_SCOPE_AGENT);

        // walk predecessors, accumulating aggregates until a prefix is found
        int p = wave - 1;
        for (;;) {
            int f = 0;
            if (lane == 0) {
                f = __hip_atomic_load(flags + p, __ATOMIC_RELAXED, __HIP_MEMORY_SCOPE_AGENT);
                while (f == 0) {
                    __builtin_amdgcn_s_sleep(1);
                    f = __hip_atomic_load(flags + p, __ATOMIC_RELAXED, __HIP_MEMORY_SCOPE_AGENT);
                }
            }
            f = __shfl(f, 0, 64);
            __threadfence();
            const float* sk  = (f == 2 ? prefK  : aggK)  + (size_t)p * Dd + dg * 4;
            const float* skv = (f == 2 ? prefKV : aggKV) + (size_t)p * Dd + dg * 4;
            P.x   += __hip_atomic_load(sk  + 0, __ATOMIC_RELAXED, __HIP_MEMORY_SCOPE_AGENT);
            P.y   += __hip_atomic_load(sk  + 1, __ATOMIC_RELAXED, __HIP_MEMORY_SCOPE_AGENT);
            P.z   += __hip_atomic_load(sk  + 2, __ATOMIC_RELAXED, __HIP_MEMORY_SCOPE_AGENT);
            P.w   += __hip_atomic_load(sk  + 3, __ATOMIC_RELAXED, __HIP_MEMORY_SCOPE_AGENT);
            Pkv.x += __hip_atomic_load(skv + 0, __ATOMIC_RELAXED, __HIP_MEMORY_SCOPE_AGENT);
            Pkv.y += __hip_atomic_load(skv + 1, __ATOMIC_RELAXED, __HIP_MEMORY_SCOPE_AGENT);
            Pkv.z += __hip_atomic_load(skv + 2, __ATOMIC_RELAXED, __HIP_MEMORY_SCOPE_AGENT);
            Pkv.w += __hip_atomic_load(skv + 3, __ATOMIC_RELAXED, __HIP_MEMORY_SCOPE_AGENT);
            if (f == 2) break;
            --p;
        }

        // publish our inclusive prefix so successors can stop here
        if (rg == 0) {
            __hip_atomic_store(prefK  + pbase + 0, P.x + ak.x,    __ATOMIC_RELAXED, __HIP_MEMORY_SCOPE_AGENT);
            __hip_atomic_store(prefK  + pbase + 1, P.y + ak.y,    __ATOMIC_RELAXED, __HIP_MEMORY_SCOPE_AGENT);
            __hip_atomic_store(prefK  + pbase + 2, P.z + ak.z,    __ATOMIC_RELAXED, __HIP_MEMORY_SCOPE_AGENT);
            __hip_atomic_store(prefK  + pbase + 3, P.w + ak.w,    __ATOMIC_RELAXED, __HIP_MEMORY_SCOPE_AGENT);
            __hip_atomic_store(prefKV + pbase + 0, Pkv.x + akv.x, __ATOMIC_RELAXED, __HIP_MEMORY_SCOPE_AGENT);
            __hip_atomic_store(prefKV + pbase + 1, Pkv.y + akv.y, __ATOMIC_RELAXED, __HIP_MEMORY_SCOPE_AGENT);
            __hip_atomic_store(prefKV + pbase + 2, Pkv.z + akv.z, __ATOMIC_RELAXED, __HIP_MEMORY_SCOPE_AGENT);
            __hip_atomic_store(prefKV + pbase + 3, Pkv.w + akv.w, __ATOMIC_RELAXED, __HIP_MEMORY_SCOPE_AGENT);
        }
        __threadfence();
        if (lane == 0)
            __hip_atomic_store(flags + wave, 2, __ATOMIC_RELAXED, __HIP_MEMORY_SCOPE_AGENT);
    }

    // ---------------- phase 3: scan + output, seeded with prefix ----------------
    float4 Sk = P, Skv = Pkv;
    for (int i = 0; i < CHUNK; i += 4) {
        const int l = l0 + i + rg;
        const size_t off = ((size_t)bh * Lseq + l) * Dd + dg * 4;
        const float4 q4 = *(const float4*)(q + off);
        const float4 k4 = *(const float4*)(k + off);
        const float4 v4 = *(const float4*)(v + off);
        const float m = mask[(size_t)b * Lseq + l];

        float4 fq, a, av;
        fq.x = phi(q4.x); fq.y = phi(q4.y); fq.z = phi(q4.z); fq.w = phi(q4.w);
        a.x = phi(k4.x) * m; av.x = a.x * (v4.x * m);
        a.y = phi(k4.y) * m; av.y = a.y * (v4.y * m);
        a.z = phi(k4.z) * m; av.z = a.z * (v4.z * m);
        a.w = phi(k4.w) * m; av.w = a.w * (v4.w * m);

        // inclusive scan across the 4 row groups (strides 16, 32)
        float t;
        t = __shfl_up(a.x,  16, 64); if (rg >= 1) a.x  += t;
        t = __shfl_up(a.y,  16, 64); if (rg >= 1) a.y  += t;
        t = __shfl_up(a.z,  16, 64); if (rg >= 1) a.z  += t;
        t = __shfl_up(a.w,  16, 64); if (rg >= 1) a.w  += t;
        t = __shfl_up(av.x, 16, 64); if (rg >= 1) av.x += t;
        t = __shfl_up(av.y, 16, 64); if (rg >= 1) av.y += t;
        t = __shfl_up(av.z, 16, 64); if (rg >= 1) av.z += t;
        t = __shfl_up(av.w, 16, 64); if (rg >= 1) av.w += t;
        t = __shfl_up(a.x,  32, 64); if (rg >= 2) a.x  += t;
        t = __shfl_up(a.y,  32, 64); if (rg >= 2) a.y  += t;
        t = __shfl_up(a.z,  32, 64); if (rg >= 2) a.z  += t;
        t = __shfl_up(a.w,  32, 64); if (rg >= 2) a.w  += t;
        t = __shfl_up(av.x, 32, 64); if (rg >= 2) av.x += t;
        t = __shfl_up(av.y, 32, 64); if (rg >= 2) av.y += t;
        t = __shfl_up(av.z, 32, 64); if (rg >= 2) av.z += t;
        t = __shfl_up(av.w, 32, 64); if (rg >= 2) av.w += t;

        const float4 ik  = make_float4(Sk.x + a.x,   Sk.y + a.y,   Sk.z + a.z,   Sk.w + a.w);
        const float4 ikv = make_float4(Skv.x + av.x, Skv.y + av.y, Skv.z + av.z, Skv.w + av.w);

        // z = (sum_d phi(q)*k_cumsum + EPS) * mask (reduce over 16 dg lanes)
        float p = fq.x * ik.x + fq.y * ik.y + fq.z * ik.z + fq.w * ik.w;
        p += __shfl_xor(p, 1, 64);
        p += __shfl_xor(p, 2, 64);
        p += __shfl_xor(p, 4, 64);
        p += __shfl_xor(p, 8, 64);
        const float z = (p + EPS) * m;
        const float inv = 1.0f / z;

        float4 o4;
        o4.x = fq.x * ikv.x * inv;
        o4.y = fq.y * ikv.y * inv;
        o4.z = fq.z * ikv.z * inv;
        o4.w = fq.w * ikv.w * inv;
        *(float4*)(out + off) = o4;

        // advance running prefix by this 4-row group's total (value at rg==3)
        Sk.x  += __shfl(a.x,  48 + dg, 64);
        Sk.y  += __shfl(a.y,  48 + dg, 64);
        Sk.z  += __shfl(a.z,  48 + dg, 64);
        Sk.w  += __shfl(a.w,  48 + dg, 64);
        Skv.x += __shfl(av.x, 48 + dg, 64);
        Skv.y += __shfl(av.y, 48 + dg, 64);
        Skv.z += __shfl(av.z, 48 + dg, 64);
        Skv.w += __shfl(av.w, 48 + dg, 64);
    }
}

extern "C" void kernel_launch(void* const* d_in, const int* in_sizes, int n_in,
                              void* d_out, int out_size, void* d_ws, size_t ws_size,
                              hipStream_t stream) {
    const float* q    = (const float*)d_in[0];
    const float* k    = (const float*)d_in[1];
    const float* v    = (const float*)d_in[2];
    const float* mask = (const float*)d_in[3];
    float* out = (float*)d_out;

    // ws layout: [flags NCHUNKS][ticket 1][pad->256B][aggK][aggKV][prefK][prefKV]
    // total = 16.4 KB + 4 MiB
    uint8_t* ws = (uint8_t*)d_ws;
    int* flags  = (int*)ws;
    int* ticket = flags + NCHUNKS;
    size_t payload_off = (((size_t)(NCHUNKS + 1) * sizeof(int)) + 255) & ~(size_t)255;
    float* aggK   = (float*)(ws + payload_off);
    float* aggKV  = aggK  + (size_t)NCHUNKS * Dd;
    float* prefK  = aggKV + (size_t)NCHUNKS * Dd;
    float* prefKV = prefK + (size_t)NCHUNKS * Dd;

    // d_ws is re-poisoned to 0xAA before every launch: flags/ticket MUST be
    // zeroed on-stream (graph-capturable memset node).
    hipMemsetAsync(flags, 0, (size_t)(NCHUNKS + 1) * sizeof(int), stream);

    la_onepass<<<NBLK, 256, 0, stream>>>(q, k, v, mask, flags, ticket,
                                         aggK, aggKV, prefK, prefKV, out);
}

// Round 3
// 451.242 us; speedup vs baseline: 4.0276x; 4.0276x over previous
//
#include <hip/hip_runtime.h>
#include <cstdint>

#define EPS 1e-6f

constexpr int Bsz = 4, Hn = 16, Lseq = 8192, Dd = 64;
constexpr int BH = Bsz * Hn;              // 64
constexpr int CHUNK = 64;                 // rows per wave-chunk (was 128; halved for occupancy)
constexpr int CPB = Lseq / CHUNK;         // 128 chunks per (b,h)
constexpr int NCHUNKS = BH * CPB;         // 8192
constexpr int WPB = 4;                    // waves per block
constexpr int NBLK = NCHUNKS / WPB;       // 2048 blocks -> 32 waves/CU (100% cap)
constexpr int QCH = CPB / 4;              // 32 chunks per scan-quarter

// feature map: x>0 ? x+1 : exp(x). __expf -> v_exp_f32
__device__ __forceinline__ float phi(float x) {
    return x > 0.0f ? x + 1.0f : __expf(x);
}

// ---------------- kernel 1: per-chunk aggregates (order-free) ----------------
__global__ __launch_bounds__(256) void partials_kernel(
    const float* __restrict__ k, const float* __restrict__ v,
    const float* __restrict__ mask,
    float* __restrict__ pk, float* __restrict__ pkv)
{
    const int wave = blockIdx.x * WPB + (threadIdx.x >> 6);
    const int lane = threadIdx.x & 63;
    const int rg = lane >> 4;          // row group 0..3
    const int dg = lane & 15;          // dims [4*dg, 4*dg+4)
    const int bh = wave / CPB;
    const int c  = wave % CPB;
    const int b  = bh / Hn;
    const int l0 = c * CHUNK;

    float4 ak  = make_float4(0.f, 0.f, 0.f, 0.f);
    float4 akv = make_float4(0.f, 0.f, 0.f, 0.f);

    #pragma unroll 4
    for (int i = 0; i < CHUNK; i += 4) {
        const int l = l0 + i + rg;
        const size_t off = ((size_t)bh * Lseq + l) * Dd + dg * 4;
        const float4 k4 = *(const float4*)(k + off);
        const float4 v4 = *(const float4*)(v + off);
        const float m = mask[(size_t)b * Lseq + l];
        float t;
        t = phi(k4.x) * m; ak.x += t; akv.x += t * (v4.x * m);
        t = phi(k4.y) * m; ak.y += t; akv.y += t * (v4.y * m);
        t = phi(k4.z) * m; ak.z += t; akv.z += t * (v4.z * m);
        t = phi(k4.w) * m; ak.w += t; akv.w += t * (v4.w * m);
    }

    // reduce across the 4 row groups — butterfly (xor 16, 32)
    #pragma unroll
    for (int o = 16; o <= 32; o <<= 1) {
        ak.x  += __shfl_xor(ak.x,  o, 64);
        ak.y  += __shfl_xor(ak.y,  o, 64);
        ak.z  += __shfl_xor(ak.z,  o, 64);
        ak.w  += __shfl_xor(ak.w,  o, 64);
        akv.x += __shfl_xor(akv.x, o, 64);
        akv.y += __shfl_xor(akv.y, o, 64);
        akv.z += __shfl_xor(akv.z, o, 64);
        akv.w += __shfl_xor(akv.w, o, 64);
    }

    if (rg == 0) {
        const size_t o = (size_t)wave * Dd + dg * 4;
        *(float4*)(pk  + o) = ak;
        *(float4*)(pkv + o) = akv;
    }
}

// ------------- kernel 2: exclusive scan over chunk aggregates ---------------
// One block per (b,h). Thread (qc, d): qc = quarter (32 chunks), d = dim.
// All loads batched (independent), scan in registers, quarter totals via LDS.
__global__ __launch_bounds__(256) void scan_kernel(
    float* __restrict__ pk, float* __restrict__ pkv)
{
    const int bh = blockIdx.x;
    const int d  = threadIdx.x & 63;
    const int qc = threadIdx.x >> 6;       // 0..3
    const size_t base = ((size_t)bh * CPB + qc * QCH) * Dd + d;

    float vk[QCH], vkv[QCH];
    #pragma unroll
    for (int j = 0; j < QCH; ++j) {
        vk[j]  = pk [base + (size_t)j * Dd];
        vkv[j] = pkv[base + (size_t)j * Dd];
    }

    // register exclusive scan within the quarter
    float sk = 0.f, skv = 0.f;
    #pragma unroll
    for (int j = 0; j < QCH; ++j) {
        const float tk = vk[j], tkv = vkv[j];
        vk[j] = sk;   sk  += tk;
        vkv[j] = skv; skv += tkv;
    }

    // exchange quarter totals
    __shared__ float tK[4][64], tKV[4][64];
    tK[qc][d] = sk; tKV[qc][d] = skv;
    __syncthreads();
    float offk = 0.f, offkv = 0.f;
    #pragma unroll
    for (int t = 0; t < 3; ++t) {
        if (t < qc) { offk += tK[t][d]; offkv += tKV[t][d]; }
    }

    #pragma unroll
    for (int j = 0; j < QCH; ++j) {
        pk [base + (size_t)j * Dd] = vk[j]  + offk;
        pkv[base + (size_t)j * Dd] = vkv[j] + offkv;
    }
}

// ---------------- kernel 3: final pass with exact inclusive prefix -----------
__global__ __launch_bounds__(256) void final_kernel(
    const float* __restrict__ q, const float* __restrict__ k,
    const float* __restrict__ v, const float* __restrict__ mask,
    const float* __restrict__ pk, const float* __restrict__ pkv,
    float* __restrict__ out)
{
    const int wave = blockIdx.x * WPB + (threadIdx.x >> 6);
    const int lane = threadIdx.x & 63;
    const int rg = lane >> 4;
    const int dg = lane & 15;
    const int bh = wave / CPB;
    const int c  = wave % CPB;
    const int b  = bh / Hn;
    const int l0 = c * CHUNK;

    const size_t po = (size_t)wave * Dd + dg * 4;
    float4 Sk  = *(const float4*)(pk  + po);   // exclusive prefix for this chunk
    float4 Skv = *(const float4*)(pkv + po);

    for (int i = 0; i < CHUNK; i += 4) {
        const int l = l0 + i + rg;
        const size_t off = ((size_t)bh * Lseq + l) * Dd + dg * 4;
        const float4 q4 = *(const float4*)(q + off);
        const float4 k4 = *(const float4*)(k + off);
        const float4 v4 = *(const float4*)(v + off);
        const float m = mask[(size_t)b * Lseq + l];

        float4 fq, a, av;
        fq.x = phi(q4.x); fq.y = phi(q4.y); fq.z = phi(q4.z); fq.w = phi(q4.w);
        a.x = phi(k4.x) * m; av.x = a.x * (v4.x * m);
        a.y = phi(k4.y) * m; av.y = a.y * (v4.y * m);
        a.z = phi(k4.z) * m; av.z = a.z * (v4.z * m);
        a.w = phi(k4.w) * m; av.w = a.w * (v4.w * m);

        // inclusive scan across the 4 row groups (strides 16, 32)
        float t;
        t = __shfl_up(a.x,  16, 64); if (rg >= 1) a.x  += t;
        t = __shfl_up(a.y,  16, 64); if (rg >= 1) a.y  += t;
        t = __shfl_up(a.z,  16, 64); if (rg >= 1) a.z  += t;
        t = __shfl_up(a.w,  16, 64); if (rg >= 1) a.w  += t;
        t = __shfl_up(av.x, 16, 64); if (rg >= 1) av.x += t;
        t = __shfl_up(av.y, 16, 64); if (rg >= 1) av.y += t;
        t = __shfl_up(av.z, 16, 64); if (rg >= 1) av.z += t;
        t = __shfl_up(av.w, 16, 64); if (rg >= 1) av.w += t;
        t = __shfl_up(a.x,  32, 64); if (rg >= 2) a.x  += t;
        t = __shfl_up(a.y,  32, 64); if (rg >= 2) a.y  += t;
        t = __shfl_up(a.z,  32, 64); if (rg >= 2) a.z  += t;
        t = __shfl_up(a.w,  32, 64); if (rg >= 2) a.w  += t;
        t = __shfl_up(av.x, 32, 64); if (rg >= 2) av.x += t;
        t = __shfl_up(av.y, 32, 64); if (rg >= 2) av.y += t;
        t = __shfl_up(av.z, 32, 64); if (rg >= 2) av.z += t;
        t = __shfl_up(av.w, 32, 64); if (rg >= 2) av.w += t;

        const float4 ik  = make_float4(Sk.x + a.x,   Sk.y + a.y,   Sk.z + a.z,   Sk.w + a.w);
        const float4 ikv = make_float4(Skv.x + av.x, Skv.y + av.y, Skv.z + av.z, Skv.w + av.w);

        // z = (sum_d phi(q)*k_cumsum + EPS) * mask (reduce over 16 dg lanes)
        float p = fq.x * ik.x + fq.y * ik.y + fq.z * ik.z + fq.w * ik.w;
        p += __shfl_xor(p, 1, 64);
        p += __shfl_xor(p, 2, 64);
        p += __shfl_xor(p, 4, 64);
        p += __shfl_xor(p, 8, 64);
        const float z = (p + EPS) * m;
        const float inv = 1.0f / z;

        float4 o4;
        o4.x = fq.x * ikv.x * inv;
        o4.y = fq.y * ikv.y * inv;
        o4.z = fq.z * ikv.z * inv;
        o4.w = fq.w * ikv.w * inv;
        *(float4*)(out + off) = o4;

        // advance running prefix by this 4-row group's total (value at rg==3)
        Sk.x  += __shfl(a.x,  48 + dg, 64);
        Sk.y  += __shfl(a.y,  48 + dg, 64);
        Sk.z  += __shfl(a.z,  48 + dg, 64);
        Sk.w  += __shfl(a.w,  48 + dg, 64);
        Skv.x += __shfl(av.x, 48 + dg, 64);
        Skv.y += __shfl(av.y, 48 + dg, 64);
        Skv.z += __shfl(av.z, 48 + dg, 64);
        Skv.w += __shfl(av.w, 48 + dg, 64);
    }
}

extern "C" void kernel_launch(void* const* d_in, const int* in_sizes, int n_in,
                              void* d_out, int out_size, void* d_ws, size_t ws_size,
                              hipStream_t stream) {
    const float* q    = (const float*)d_in[0];
    const float* k    = (const float*)d_in[1];
    const float* v    = (const float*)d_in[2];
    const float* mask = (const float*)d_in[3];
    float* out = (float*)d_out;

    // workspace: 2 arrays of NCHUNKS*64 floats = 4 MiB total; fully written by
    // partials before scan reads them -> no memset needed.
    float* pk  = (float*)d_ws;
    float* pkv = pk + (size_t)NCHUNKS * Dd;

    partials_kernel<<<NBLK, 256, 0, stream>>>(k, v, mask, pk, pkv);
    scan_kernel<<<BH, 256, 0, stream>>>(pk, pkv);
    final_kernel<<<NBLK, 256, 0, stream>>>(q, k, v, mask, pk, pkv, out);
}